// Round 11
// baseline (389.180 us; speedup 1.0000x reference)
//
#include <hip/hip_runtime.h>
#include <hip/hip_fp16.h>

// CTC forward loss. B=64, T=2000, C=128 (blank=127), Lmax=200, S=401.
// v11: DUAL-BATCH CONSUMER WAVE. 32 blocks x 256 thr; block handles batches
// 2*bid, 2*bid+1.
//   Evidence chain: consumer round2 costs ~365cyc vs ~110 issue + ~36 dep;
//   nulls: -16% instrs (v7), counted lgkmcnt+sched_barrier+setprio (v8),
//   producer latency (v9, worse), HW-SMT pairing (v5, worse), barrier count
//   (v10, -4us only). The stall is insensitive to intra-wave instruction mix
//   -> fill it with INDEPENDENT work in the same wave: wave 0 runs BOTH
//   batches' recursions, interleaved per round (deterministic ILP, no
//   scheduler dependence; consumer still owns SIMD0 alone).
//   wave 0      : dual alpha recursion, CState SA/SB (named fields), v4
//                 half-format pairs (LDS halved; cvts are proven-null filler).
//   waves 1..3  : producers for both batches: 6 pairs x 2 batches each, all
//                 24 row loads issued up front, branch-free bodies, uniform
//                 per-batch guards; 4-bpermute half2 gather (v4 proven).
// Sync: one __syncthreads() per chunk; per-batch double buffers parity k&1;
// garbage pairs -> scratch slots 16/17 or clamped rows, never read.

#define LOG2E 1.44269504088896340736f
#define LN2F  0.69314718055994530942f

namespace {

constexpr int Bc = 64, Tc = 2000, Cc = 128, Lmaxc = 200;
constexpr int PAIRB = 1024;                  // bytes per pair (64 lanes x 16)
constexpr int CHP = 16;                      // pairs per chunk (32 steps)
constexpr int CHPA = 18;                     // allocated pair slots (2 scratch)
constexpr int CHB = CHPA * PAIRB;            // 18 KB per buffer

struct CState {
  float a0, a1, a2, a3, a4, a5, a6, a7;
  float s7d, zsd, corr;
  float sk0, sk1, sk2, sk3, skHn;
  int E, epd;
};

__device__ __forceinline__ float dpp_shr1_f(float x) {  // lane i <- i-1, lane0 <- 0
  return __int_as_float(
      __builtin_amdgcn_update_dpp(0, __float_as_int(x), 0x138, 0xF, 0xF, true));
}
__device__ __forceinline__ float dpp_shl1_f(float x) {  // lane i <- i+1, lane63 <- 0
  return __int_as_float(
      __builtin_amdgcn_update_dpp(0, __float_as_int(x), 0x130, 0xF, 0xF, true));
}
__device__ __forceinline__ int dpp_shr1_i(int x) {
  return __builtin_amdgcn_update_dpp(0, x, 0x138, 0xF, 0xF, true);
}
template <int CTRL>
__device__ __forceinline__ float dpp_add(float v) {
  return v + __int_as_float(
      __builtin_amdgcn_update_dpp(0, __float_as_int(v), CTRL, 0xF, 0xF, true));
}
__device__ __forceinline__ float wave_sum_bcast(float v) {  // full-wave sum
  v = dpp_add<0x111>(v);
  v = dpp_add<0x112>(v);
  v = dpp_add<0x114>(v);
  v = dpp_add<0x118>(v);
  v = dpp_add<0x142>(v);
  v = dpp_add<0x143>(v);
  return __int_as_float(__builtin_amdgcn_readlane(__float_as_int(v), 63));
}

__global__ __launch_bounds__(256, 1) void ctc_fused_kernel(
    const float* __restrict__ y, const int* __restrict__ y_true,
    const int* __restrict__ in_len, const int* __restrict__ lab_len,
    float* __restrict__ out) {
  __shared__ __align__(16) char bufs[2][2][CHB];   // [batch][parity] 72 KB
  __shared__ __align__(16) float blkb[2][2][40];   // blank probs

  const int bid = blockIdx.x;
  const int bA = 2 * bid, bB = 2 * bid + 1;
  const int wv = threadIdx.x >> 6, lane = threadIdx.x & 63;
  const int lane16 = lane * 16;

  auto clampLen = [](int L) { return L < 1 ? 1 : (L > Tc ? Tc : L); };
  const int lenA = clampLen(in_len[bA]);
  const int lenB = clampLen(in_len[bB]);
  const int RA = (lenA - 1) >> 1, RB = (lenB - 1) >> 1;
  const int lfA = (lenA - 1) & 1, lfB = (lenB - 1) & 1;
  const int NCgA = ((RA + lfA) + CHP - 1) / CHP;
  const int NCgB = ((RB + lfB) + CHP - 1) / CHP;
  const int cfA = RA / CHP, cfB = RB / CHP;
  const int kmaxc = cfA > cfB ? cfA : cfB;
  const int* labsA = y_true + bA * Lmaxc;
  const int* labsB = y_true + bB * Lmaxc;
  const float* yrowA = y + (size_t)bA * Tc * Cc + 2 * lane;
  const float* yrowB = y + (size_t)bB * Tc * Cc + 2 * lane;

  // ---- producer-side label classes, both batches (v4 fix() semantics) ----
  int pbase = 4 * lane;
  if (pbase > Lmaxc - 4) pbase = Lmaxc - 4;
  const int4 LwA = *(const int4*)(labsA + pbase);
  const int4 LwB = *(const int4*)(labsB + pbase);
  auto fix = [&](int v, int idx, int last) {
    int r = (idx > Lmaxc - 1) ? last : v;
    return r < 0 ? 0 : r;
  };
  const int cA0 = fix(LwA.x, 4 * lane, LwA.w), cA1 = fix(LwA.y, 4 * lane + 1, LwA.w);
  const int cA2 = fix(LwA.z, 4 * lane + 2, LwA.w), cA3 = fix(LwA.w, 4 * lane + 3, LwA.w);
  const int cB0 = fix(LwB.x, 4 * lane, LwB.w), cB1 = fix(LwB.y, 4 * lane + 1, LwB.w);
  const int cB2 = fix(LwB.z, 4 * lane + 2, LwB.w), cB3 = fix(LwB.w, 4 * lane + 3, LwB.w);

  // softmax + half2-gather (4 bpermutes) -> packed 4 halves; bl = blank prob
  auto pack2 = [&](int p0, int p1, int p2, int p3, float2 yy, float& bl) -> uint2 {
    float e0 = exp2f(fminf(yy.x * LOG2E, 50.f));
    float e1 = exp2f(fminf(yy.y * LOG2E, 50.f));
    const float rs = 1.0f / wave_sum_bcast(e0 + e1);
    unsigned q2 =
        __builtin_bit_cast(unsigned, __floats2half2_rn(e0 * rs, e1 * rs));
    unsigned g0 = (unsigned)__builtin_amdgcn_ds_bpermute((p0 >> 1) << 2, (int)q2);
    unsigned g1 = (unsigned)__builtin_amdgcn_ds_bpermute((p1 >> 1) << 2, (int)q2);
    unsigned g2 = (unsigned)__builtin_amdgcn_ds_bpermute((p2 >> 1) << 2, (int)q2);
    unsigned g3 = (unsigned)__builtin_amdgcn_ds_bpermute((p3 >> 1) << 2, (int)q2);
    unsigned h0 = (p0 & 1) ? (g0 >> 16) : (g0 & 0xFFFFu);
    unsigned h1 = (p1 & 1) ? (g1 >> 16) : (g1 & 0xFFFFu);
    unsigned h2 = (p2 & 1) ? (g2 >> 16) : (g2 & 0xFFFFu);
    unsigned h3 = (p3 & 1) ? (g3 >> 16) : (g3 & 0xFFFFu);
    bl = e1 * rs;  // lane 63 holds class-127 (blank) prob
    return make_uint2(h0 | (h1 << 16), h2 | (h3 << 16));
  };

  // producer: wave wv packs local pairs wv-1 + 3i (i<6) for BOTH batches of
  // chunk kp. All 24 row loads issued first (one HBM latency exposure);
  // branch-free bodies; uniform per-batch guards only. Garbage pairs land in
  // scratch slots 16/17 or clamped rows -- never read by the consumer.
  auto produce2 = [&](int kp) {
    const bool dA = kp < NCgA, dB = kp < NCgB;
    char* pbA = &bufs[0][kp & 1][0];
    char* pbB = &bufs[1][kp & 1][0];
    float* bbA = blkb[0][kp & 1];
    float* bbB = blkb[1][kp & 1];
    const int pq0 = wv - 1;              // 0,1,2
    const int tbase = 32 * kp + 1;       // step of slot A of local pair 0
    float2 vA0, uA0, vA1, uA1, vA2, uA2, vA3, uA3, vA4, uA4, vA5, uA5;
    float2 vB0, uB0, vB1, uB1, vB2, uB2, vB3, uB3, vB4, uB4, vB5, uB5;
#define LOADP(yr, i, va, ua)                                \
  {                                                         \
    int tA_ = tbase + 2 * (pq0 + 3 * (i));                  \
    int tB_ = tA_ + 1;                                      \
    tA_ = tA_ > Tc - 1 ? Tc - 1 : tA_;                      \
    tB_ = tB_ > Tc - 1 ? Tc - 1 : tB_;                      \
    va = *(const float2*)((yr) + (size_t)tA_ * Cc);         \
    ua = *(const float2*)((yr) + (size_t)tB_ * Cc);         \
  }
    if (dA) {
      LOADP(yrowA, 0, vA0, uA0) LOADP(yrowA, 1, vA1, uA1)
      LOADP(yrowA, 2, vA2, uA2) LOADP(yrowA, 3, vA3, uA3)
      LOADP(yrowA, 4, vA4, uA4) LOADP(yrowA, 5, vA5, uA5)
    }
    if (dB) {
      LOADP(yrowB, 0, vB0, uB0) LOADP(yrowB, 1, vB1, uB1)
      LOADP(yrowB, 2, vB2, uB2) LOADP(yrowB, 3, vB3, uB3)
      LOADP(yrowB, 4, vB4, uB4) LOADP(yrowB, 5, vB5, uB5)
    }
#undef LOADP
#define PACKP(q0_, q1_, q2_, q3_, pb, bb, i, va, ua)                   \
  {                                                                    \
    const int pq = pq0 + 3 * (i);                                      \
    float blA_, blB_;                                                  \
    const uint2 mA = pack2(q0_, q1_, q2_, q3_, va, blA_);              \
    const uint2 mB = pack2(q0_, q1_, q2_, q3_, ua, blB_);              \
    *(uint4*)(pb + pq * PAIRB + lane16) =                              \
        make_uint4(mA.x, mA.y, mB.x, mB.y);                            \
    if (lane == 63) *(float2*)(bb + 2 * pq) = make_float2(blA_, blB_); \
  }
    if (dA) {
      PACKP(cA0, cA1, cA2, cA3, pbA, bbA, 0, vA0, uA0)
      PACKP(cA0, cA1, cA2, cA3, pbA, bbA, 1, vA1, uA1)
      PACKP(cA0, cA1, cA2, cA3, pbA, bbA, 2, vA2, uA2)
      PACKP(cA0, cA1, cA2, cA3, pbA, bbA, 3, vA3, uA3)
      PACKP(cA0, cA1, cA2, cA3, pbA, bbA, 4, vA4, uA4)
      PACKP(cA0, cA1, cA2, cA3, pbA, bbA, 5, vA5, uA5)
    }
    if (dB) {
      PACKP(cB0, cB1, cB2, cB3, pbB, bbB, 0, vB0, uB0)
      PACKP(cB0, cB1, cB2, cB3, pbB, bbB, 1, vB1, uB1)
      PACKP(cB0, cB1, cB2, cB3, pbB, bbB, 2, vB2, uB2)
      PACKP(cB0, cB1, cB2, cB3, pbB, bbB, 3, vB3, uB3)
      PACKP(cB0, cB1, cB2, cB3, pbB, bbB, 4, vB4, uB4)
      PACKP(cB0, cB1, cB2, cB3, pbB, bbB, 5, vB5, uB5)
    }
#undef PACKP
  };

  // ---- consumer-side per-lane state, both batches ----
  const int llA = lab_len[bA], llB = lab_len[bB];
  auto labc = [&](const int* L, int l) -> int {
    int lc = l < 0 ? 0 : (l > Lmaxc - 1 ? Lmaxc - 1 : l);
    int c = L[lc];
    return c < 0 ? 0 : c;
  };
  CState SA{}, SB{};
  {
    const int c0i = labc(labsA, 4 * lane), c1i = labc(labsA, 4 * lane + 1);
    const int c2i = labc(labsA, 4 * lane + 2), c3i = labc(labsA, 4 * lane + 3);
    const int cm1 = labc(labsA, 4 * lane - 1), cm2 = labc(labsA, 4 * lane - 2);
    SA.sk0 = (4 * lane >= 1 && c0i != cm1) ? 1.f : 0.f;
    SA.sk1 = (c1i != c0i) ? 1.f : 0.f;
    SA.sk2 = (c2i != c1i) ? 1.f : 0.f;
    SA.sk3 = (c3i != c2i) ? 1.f : 0.f;
    float skH = (lane >= 1 && cm1 != cm2) ? 1.f : 0.f;
    SA.skHn = dpp_shl1_f(skH);
  }
  {
    const int c0i = labc(labsB, 4 * lane), c1i = labc(labsB, 4 * lane + 1);
    const int c2i = labc(labsB, 4 * lane + 2), c3i = labc(labsB, 4 * lane + 3);
    const int cm1 = labc(labsB, 4 * lane - 1), cm2 = labc(labsB, 4 * lane - 2);
    SB.sk0 = (4 * lane >= 1 && c0i != cm1) ? 1.f : 0.f;
    SB.sk1 = (c1i != c0i) ? 1.f : 0.f;
    SB.sk2 = (c2i != c1i) ? 1.f : 0.f;
    SB.sk3 = (c3i != c2i) ? 1.f : 0.f;
    float skH = (lane >= 1 && cm1 != cm2) ? 1.f : 0.f;
    SB.skHn = dpp_shl1_f(skH);
  }

  if (wv == 0) {  // seed both batches from y row t=0 (row 0 is never packed)
    {
      const float* y0 = y + (size_t)bA * Tc * Cc + 2 * lane;
      float e0 = exp2f(fminf(y0[0] * LOG2E, 50.f));
      float e1 = exp2f(fminf(y0[1] * LOG2E, 50.f));
      const float rs = 1.0f / wave_sum_bcast(e0 + e1);
      int l0 = labsA[0];
      l0 = l0 < 0 ? 0 : l0;
      float ev = (l0 & 1) ? e1 : e0;
      float q0 = __int_as_float(__builtin_amdgcn_readlane(__float_as_int(ev), l0 >> 1)) * rs;
      float qb = __int_as_float(__builtin_amdgcn_readlane(__float_as_int(e1), 63)) * rs;
      if (lane == 0) { SA.a0 = qb; SA.a1 = q0; }
    }
    {
      const float* y0 = y + (size_t)bB * Tc * Cc + 2 * lane;
      float e0 = exp2f(fminf(y0[0] * LOG2E, 50.f));
      float e1 = exp2f(fminf(y0[1] * LOG2E, 50.f));
      const float rs = 1.0f / wave_sum_bcast(e0 + e1);
      int l0 = labsB[0];
      l0 = l0 < 0 ? 0 : l0;
      float ev = (l0 & 1) ? e1 : e0;
      float q0 = __int_as_float(__builtin_amdgcn_readlane(__float_as_int(ev), l0 >> 1)) * rs;
      float qb = __int_as_float(__builtin_amdgcn_readlane(__float_as_int(e1), 63)) * rs;
      if (lane == 0) { SB.a0 = qb; SB.a1 = q0; }
    }
  }
  SA.s7d = dpp_shr1_f(SA.a7);
  SA.zsd = dpp_shr1_f(fmaf(SA.skHn, SA.a5, SA.a6));
  SA.epd = 0;
  SA.corr = (lane == 0) ? 0.f : 1.f;
  SB.s7d = dpp_shr1_f(SB.a7);
  SB.zsd = dpp_shr1_f(fmaf(SB.skHn, SB.a5, SB.a6));
  SB.epd = 0;
  SB.corr = (lane == 0) ? 0.f : 1.f;

  // pair-round: 2 lattice steps from one 16B half-slot + f32 blank pair
  auto round2 = [&](CState& S, uint4 rw, float2 bl, bool renorm) {
    float2 aLo = __half22float2(*(__half2*)&rw.x);
    float2 aHi = __half22float2(*(__half2*)&rw.y);
    float2 bLo = __half22float2(*(__half2*)&rw.z);
    float2 bHi = __half22float2(*(__half2*)&rw.w);
    const float qbA = bl.x, qbB = bl.y;
    const float qhA = dpp_shr1_f(aHi.y);  // halo label prob (VALU pipe)
    const float w7 = S.s7d * S.corr;
    const float hA = fmaf(S.corr, S.zsd, w7) * qhA;  // == (w7+w6+skH*w5)*qhA
    float n0 = (S.a0 + w7) * qbA;
    float n1 = (S.a1 + S.a0 + S.sk0 * w7) * aLo.x;
    float n2 = (S.a2 + S.a1) * qbA;
    float n3 = (S.a3 + S.a2 + S.sk1 * S.a1) * aLo.y;
    float n4 = (S.a4 + S.a3) * qbA;
    float n5 = (S.a5 + S.a4 + S.sk2 * S.a3) * aHi.x;
    float n6 = (S.a6 + S.a5) * qbA;
    float n7 = (S.a7 + S.a6 + S.sk3 * S.a5) * aHi.y;
    S.a0 = (n0 + hA) * qbB;
    S.a1 = (n1 + n0 + S.sk0 * hA) * bLo.x;
    S.a2 = (n2 + n1) * qbB;
    S.a3 = (n3 + n2 + S.sk1 * n1) * bLo.y;
    S.a4 = (n4 + n3) * qbB;
    S.a5 = (n5 + n4 + S.sk2 * n3) * bHi.x;
    S.a6 = (n6 + n5) * qbB;
    S.a7 = (n7 + n6 + S.sk3 * n5) * bHi.y;
    if (renorm) {  // every 8 steps, exact pow2
      float mx = fmaxf(fmaxf(fmaxf(S.a0, S.a1), fmaxf(S.a2, S.a3)),
                       fmaxf(fmaxf(S.a4, S.a5), fmaxf(S.a6, S.a7)));
      unsigned bits = __float_as_uint(mx);
      bool z = (bits == 0u);
      int e = (int)(bits >> 23) - 127;
      float f = __uint_as_float((254u - (bits >> 23)) << 23);  // 2^-e
      f = z ? 1.0f : f;
      S.a0 *= f; S.a1 *= f; S.a2 *= f; S.a3 *= f;
      S.a4 *= f; S.a5 *= f; S.a6 *= f; S.a7 *= f;
      S.E = z ? S.epd : (S.E + e);
    }
    S.s7d = dpp_shr1_f(S.a7);
    S.zsd = dpp_shr1_f(fmaf(S.skHn, S.a5, S.a6));
    if (renorm) {
      S.epd = dpp_shr1_i(S.E);
      int de = S.epd - S.E;
      de = de < -126 ? -126 : (de > 60 ? 60 : de);
      S.corr = __int_as_float((de + 127) << 23);
      S.corr = (lane == 0) ? 0.0f : S.corr;
    }
  };

  // dual-batch chunk consume: rounds of A and B interleaved (independent
  // chains -> scheduler fills each other's stalls). NAMED prefetch regs.
  auto consume2 = [&](int k) {
    const char* cA = &bufs[0][k & 1][0];
    const char* cB = &bufs[1][k & 1][0];
    const float* pA = blkb[0][k & 1];
    const float* pB = blkb[1][k & 1];
    uint4 rA0 = *(const uint4*)(cA + 0 * PAIRB + lane16);
    float2 lA0 = *(const float2*)(pA + 0);
    uint4 rB0 = *(const uint4*)(cB + 0 * PAIRB + lane16);
    float2 lB0 = *(const float2*)(pB + 0);
    uint4 rA1 = *(const uint4*)(cA + 1 * PAIRB + lane16);
    float2 lA1 = *(const float2*)(pA + 2);
    uint4 rB1 = *(const uint4*)(cB + 1 * PAIRB + lane16);
    float2 lB1 = *(const float2*)(pB + 2);
#pragma unroll
    for (int h = 0; h < 8; ++h) {
      uint4 qa = rA0, qb = rB0;
      float2 ba = lA0, bb = lB0;
      if (h < 7) {
        rA0 = *(const uint4*)(cA + (2 * h + 2) * PAIRB + lane16);
        lA0 = *(const float2*)(pA + (4 * h + 4));
        rB0 = *(const uint4*)(cB + (2 * h + 2) * PAIRB + lane16);
        lB0 = *(const float2*)(pB + (4 * h + 4));
      }
      round2(SA, qa, ba, false);
      round2(SB, qb, bb, false);
      uint4 qa2 = rA1, qb2 = rB1;
      float2 ba2 = lA1, bb2 = lB1;
      if (h < 7) {
        rA1 = *(const uint4*)(cA + (2 * h + 3) * PAIRB + lane16);
        lA1 = *(const float2*)(pA + (4 * h + 6));
        rB1 = *(const uint4*)(cB + (2 * h + 3) * PAIRB + lane16);
        lB1 = *(const float2*)(pB + (4 * h + 6));
      }
      round2(SA, qa2, ba2, (h & 1) == 1);
      round2(SB, qb2, bb2, (h & 1) == 1);
    }
  };

  // single-batch chunk consume (uneven-length fallback; v4 pattern)
  auto consume1 = [&](CState& S, const char* cb, const float* pb) {
    uint4 rawA = *(const uint4*)(cb + 0 * PAIRB + lane16);
    float2 blA = *(const float2*)(pb + 0);
    uint4 rawB = *(const uint4*)(cb + 1 * PAIRB + lane16);
    float2 blB = *(const float2*)(pb + 2);
#pragma unroll
    for (int h = 0; h < 8; ++h) {
      uint4 ra = rawA;
      float2 ba = blA;
      if (h < 7) {
        rawA = *(const uint4*)(cb + (2 * h + 2) * PAIRB + lane16);
        blA = *(const float2*)(pb + (4 * h + 4));
      }
      round2(S, ra, ba, false);
      uint4 rb = rawB;
      float2 bb2 = blB;
      if (h < 7) {
        rawB = *(const uint4*)(cb + (2 * h + 3) * PAIRB + lane16);
        blB = *(const float2*)(pb + (4 * h + 6));
      }
      round2(S, rb, bb2, (h & 1) == 1);
    }
  };

  // ---- pipeline: uniform barriers, producers one chunk ahead ----
  if (wv == 0) __builtin_amdgcn_s_setprio(1);
  if (wv != 0) produce2(0);
  __syncthreads();
  for (int k = 0; k < kmaxc; ++k) {
    if (wv == 0) {
      if (k < cfA && k < cfB) consume2(k);
      else if (k < cfA) consume1(SA, &bufs[0][k & 1][0], blkb[0][k & 1]);
      else if (k < cfB) consume1(SB, &bufs[1][k & 1][0], blkb[1][k & 1]);
    } else {
      produce2(k + 1);  // per-batch guards inside
    }
    __syncthreads();
  }

  if (wv != 0) return;  // producers done (no barriers past this point)

  // tail + final combine per batch
  auto finish = [&](CState& S, int sel, int Rx, int cfx, int lfx, int llx,
                    int bout) {
    const char* tb = &bufs[sel][cfx & 1][0];
    const float* pbT = blkb[sel][cfx & 1];
    const int rem = Rx - cfx * CHP;
    for (int r = 0; r < rem; ++r) {
      uint4 rw = *(const uint4*)(tb + r * PAIRB + lane16);
      float2 bl = *(const float2*)(pbT + 2 * r);
      round2(S, rw, bl, (r & 3) == 3);
    }
    if (lfx) {  // final odd step: slot A of pair Rx
      uint4 rw = *(const uint4*)(tb + rem * PAIRB + lane16);
      float blA = *(pbT + 2 * rem);
      float2 flo = __half22float2(*(__half2*)&rw.x);
      float2 fhi = __half22float2(*(__half2*)&rw.y);
      float s7 = dpp_shr1_f(S.a7);
      int ep = dpp_shr1_i(S.E);
      int de = ep - S.E;
      de = de < -126 ? -126 : (de > 60 ? 60 : de);
      float c2v = __int_as_float((de + 127) << 23);
      c2v = (lane == 0) ? 0.0f : c2v;
      float w7 = s7 * c2v;
      float n0 = (S.a0 + w7) * blA;
      float n1 = (S.a1 + S.a0 + S.sk0 * w7) * flo.x;
      float n2 = (S.a2 + S.a1) * blA;
      float n3 = (S.a3 + S.a2 + S.sk1 * S.a1) * flo.y;
      float n4 = (S.a4 + S.a3) * blA;
      float n5 = (S.a5 + S.a4 + S.sk2 * S.a3) * fhi.x;
      float n6 = (S.a6 + S.a5) * blA;
      float n7 = (S.a7 + S.a6 + S.sk3 * S.a5) * fhi.y;
      S.a0 = n0; S.a1 = n1; S.a2 = n2; S.a3 = n3;
      S.a4 = n4; S.a5 = n5; S.a6 = n6; S.a7 = n7;
    }
    // loss = -lse(alpha[2ll], alpha[2ll-1]) in log2 domain
    int sE = 2 * llx;
    int sP = sE - 1 < 0 ? 0 : sE - 1;
    int laneA = sE >> 3, jA = sE & 7;
    int laneB = sP >> 3, jB = sP & 7;
    float va = S.a0;
    if (jA == 1) va = S.a1;
    if (jA == 2) va = S.a2;
    if (jA == 3) va = S.a3;
    if (jA == 4) va = S.a4;
    if (jA == 5) va = S.a5;
    if (jA == 6) va = S.a6;
    if (jA == 7) va = S.a7;
    float vb = S.a0;
    if (jB == 1) vb = S.a1;
    if (jB == 2) vb = S.a2;
    if (jB == 3) vb = S.a3;
    if (jB == 4) vb = S.a4;
    if (jB == 5) vb = S.a5;
    if (jB == 6) vb = S.a6;
    if (jB == 7) vb = S.a7;
    float aA = __int_as_float(__builtin_amdgcn_ds_bpermute(laneA << 2, __float_as_int(va)));
    float aB = __int_as_float(__builtin_amdgcn_ds_bpermute(laneB << 2, __float_as_int(vb)));
    int EA = __builtin_amdgcn_ds_bpermute(laneA << 2, S.E);
    int EB = __builtin_amdgcn_ds_bpermute(laneB << 2, S.E);
    if (lane == 0) {
      float l1 = (aA > 0.0f) ? (float)EA + log2f(aA) : -1e30f;
      float l2 = (aB > 0.0f) ? (float)EB + log2f(aB) : -1e30f;
      float mm = fmaxf(l1, l2);
      float v = mm + log2f(exp2f(l1 - mm) + exp2f(l2 - mm));
      out[bout] = -v * LN2F;
    }
  };
  finish(SA, 0, RA, cfA, lfA, llA, bA);
  finish(SB, 1, RB, cfB, lfB, llB, bB);
}

}  // namespace

extern "C" void kernel_launch(void* const* d_in, const int* in_sizes, int n_in,
                              void* d_out, int out_size, void* d_ws, size_t ws_size,
                              hipStream_t stream) {
  const float* y = (const float*)d_in[0];   // [64,2000,128] f32
  const int* yt = (const int*)d_in[1];      // [64,200] i32
  const int* il = (const int*)d_in[2];      // [64] i32
  const int* lb = (const int*)d_in[3];      // [64] i32
  float* out = (float*)d_out;               // [64] f32
  (void)d_ws; (void)ws_size;                // no workspace needed

  hipLaunchKernelGGL(ctc_fused_kernel, dim3(Bc / 2), dim3(256), 0, stream,
                     y, yt, il, lb, out);
}